// Round 9
// baseline (450.818 us; speedup 1.0000x reference)
//
#include <hip/hip_runtime.h>
#include <hip/hip_bf16.h>
#include <math.h>

typedef __attribute__((ext_vector_type(8))) short short8;
typedef __attribute__((ext_vector_type(4))) float f32x4;

// fp32 -> bf16 round-to-nearest-even (scalar)
__device__ __forceinline__ unsigned short f2bf(float f) {
    unsigned int u = __float_as_uint(f);
    u += 0x7FFF + ((u >> 16) & 1);
    return (unsigned short)(u >> 16);
}
__device__ __forceinline__ float b2f(unsigned short s) {
    return __uint_as_float(((unsigned int)s) << 16);
}
// packed fp32x2 -> bf16x2 RNE (v_cvt_pk_bf16_f32 on gfx950)
__device__ __forceinline__ unsigned int f2bf2(float a, float b) {
    __hip_bfloat162 h = __float22bfloat162_rn(make_float2(a, b));
    return *(unsigned int*)&h;
}
// async global->LDS, 16B per lane (global_load_lds_dwordx4)
__device__ __forceinline__ void gl_lds16(const void* g, void* l) {
    __builtin_amdgcn_global_load_lds(
        (const __attribute__((address_space(1))) void*)g,
        (__attribute__((address_space(3))) void*)l, 16, 0, 0);
}

// CSR build via LDS two-level bucket sort, ZERO global atomics.
// 256 buckets x 512 nodes (covers N<=131072). bins 0..255 = dst, 256..511 = src.
// parr packed: src | (dst&511)<<17  (src < 2^17). sarr: ushort (src&511).
#define EB 8192        // edges per partition block
#define BSH 9          // node >> 9 = bucket
#define NBKT 256

__global__ __launch_bounds__(256)
void k1_hist(const int* __restrict__ src, const int* __restrict__ dst,
             int* __restrict__ bhist, int E) {
    __shared__ int hist[512];
    int t = threadIdx.x;
    hist[t] = 0; hist[t + 256] = 0;
    __syncthreads();
    int base = blockIdx.x * EB;
    int end = min(base + EB, E);
    for (int e = base + 4 * t; e < end; e += 1024) {
        if (e + 3 < end) {
            int4 d4 = *(const int4*)&dst[e];
            int4 s4 = *(const int4*)&src[e];
            atomicAdd(&hist[d4.x >> BSH], 1);
            atomicAdd(&hist[d4.y >> BSH], 1);
            atomicAdd(&hist[d4.z >> BSH], 1);
            atomicAdd(&hist[d4.w >> BSH], 1);
            atomicAdd(&hist[256 + (s4.x >> BSH)], 1);
            atomicAdd(&hist[256 + (s4.y >> BSH)], 1);
            atomicAdd(&hist[256 + (s4.z >> BSH)], 1);
            atomicAdd(&hist[256 + (s4.w >> BSH)], 1);
        } else {
            for (int q = e; q < end; ++q) {
                atomicAdd(&hist[dst[q] >> BSH], 1);
                atomicAdd(&hist[256 + (src[q] >> BSH)], 1);
            }
        }
    }
    __syncthreads();
    int* o = bhist + (size_t)blockIdx.x * 512;
    o[t] = hist[t];
    o[t + 256] = hist[t + 256];
}

// Fused: column totals over PB blocks + segmented exclusive scan (dst|src).
__global__ __launch_bounds__(1024)
void kc12(const int* __restrict__ bhist, int* __restrict__ totals,
          int* __restrict__ bbase_d, int* __restrict__ bbase_s, int PB) {
    __shared__ int part[1024];
    __shared__ int s[512];
    int t = threadIdx.x;
    int bin = t & 511, half = t >> 9;
    int sum = 0;
    for (int blk = half; blk < PB; blk += 2)
        sum += bhist[(size_t)blk * 512 + bin];
    part[t] = sum;
    __syncthreads();
    int v = 0;
    if (t < 512) {
        v = part[t] + part[t + 512];
        totals[t] = v;
        s[t] = v;
    }
    __syncthreads();
    for (int off = 1; off < 256; off <<= 1) {
        int u = 0;
        if (t < 512 && (t & 255) >= off) u = s[t - off];
        __syncthreads();
        if (t < 512) s[t] += u;
        __syncthreads();
    }
    if (t < 512) {
        int excl = s[t] - v;
        if (t < 256) bbase_d[t] = excl;
        else bbase_s[t - 256] = excl;
    }
}

// Per-bin scan over partition blocks -> scatter offsets boffT[bin][PB].
__global__ __launch_bounds__(256)
void kc3_boff(const int* __restrict__ bhist, const int* __restrict__ bbase_d,
              const int* __restrict__ bbase_s, int* __restrict__ boffT, int PB) {
    __shared__ int sums[256];
    int b = blockIdx.x;  // 0..511
    int t = threadIdx.x;
    int v = (t < PB) ? bhist[(size_t)t * 512 + b] : 0;
    sums[t] = v;
    __syncthreads();
    for (int off = 1; off < 256; off <<= 1) {
        int u = (t >= off) ? sums[t - off] : 0;
        __syncthreads();
        sums[t] += u;
        __syncthreads();
    }
    int base = (b < 256) ? bbase_d[b] : bbase_s[b - 256];
    if (t < PB) boffT[(size_t)b * PB + t] = base + sums[t] - v;
}

__global__ __launch_bounds__(256)
void k2_scatter(const int* __restrict__ src, const int* __restrict__ dst,
                const int* __restrict__ boffT, int* __restrict__ parr,
                unsigned short* __restrict__ sarr, int E, int PB) {
    __shared__ int cnt[512];
    int t = threadIdx.x;
    int blk = blockIdx.x;
    cnt[t] = boffT[(size_t)t * PB + blk];
    cnt[t + 256] = boffT[(size_t)(t + 256) * PB + blk];
    __syncthreads();
    int base = blk * EB;
    int end = min(base + EB, E);
    for (int e = base + 4 * t; e < end; e += 1024) {
        if (e + 3 < end) {
            int4 s4 = *(const int4*)&src[e];
            int4 d4 = *(const int4*)&dst[e];
            int p0 = atomicAdd(&cnt[d4.x >> BSH], 1); parr[p0] = s4.x | ((d4.x & 511) << 17);
            int p1 = atomicAdd(&cnt[d4.y >> BSH], 1); parr[p1] = s4.y | ((d4.y & 511) << 17);
            int p2 = atomicAdd(&cnt[d4.z >> BSH], 1); parr[p2] = s4.z | ((d4.z & 511) << 17);
            int p3 = atomicAdd(&cnt[d4.w >> BSH], 1); parr[p3] = s4.w | ((d4.w & 511) << 17);
            int q0 = atomicAdd(&cnt[256 + (s4.x >> BSH)], 1); sarr[q0] = (unsigned short)(s4.x & 511);
            int q1 = atomicAdd(&cnt[256 + (s4.y >> BSH)], 1); sarr[q1] = (unsigned short)(s4.y & 511);
            int q2 = atomicAdd(&cnt[256 + (s4.z >> BSH)], 1); sarr[q2] = (unsigned short)(s4.z & 511);
            int q3 = atomicAdd(&cnt[256 + (s4.w >> BSH)], 1); sarr[q3] = (unsigned short)(s4.w & 511);
        } else {
            for (int q = e; q < end; ++q) {
                int sv = src[q], dv = dst[q];
                int pd = atomicAdd(&cnt[dv >> BSH], 1);
                parr[pd] = sv | ((dv & 511) << 17);
                int ps = atomicAdd(&cnt[256 + (sv >> BSH)], 1);
                sarr[ps] = (unsigned short)(sv & 511);
            }
        }
    }
}

// Per dst-bucket (512 nodes): LDS 512-bin hist + scan -> row_off, col.
// 256 blocks x 512 threads = full GPU (R8's 128x1024 left half the CUs idle).
__global__ __launch_bounds__(512)
void k3_dst(const int* __restrict__ parr, const int* __restrict__ totals,
            const int* __restrict__ bbase_d, int* __restrict__ row_off,
            int* __restrict__ col, int N, int E) {
    __shared__ int hist[512], sc[512];
    int b = blockIdx.x, t = threadIdx.x;
    if (b == 0 && t == 0) row_off[N] = E;
    int ne = totals[b];
    int ebase = bbase_d[b];
    hist[t] = 0;
    __syncthreads();
    for (int i = t; i < ne; i += 512)
        atomicAdd(&hist[(parr[ebase + i] >> 17) & 511], 1);
    __syncthreads();
    int h = hist[t];
    sc[t] = h;
    __syncthreads();
    for (int off = 1; off < 512; off <<= 1) {
        int u = (t >= off) ? sc[t - off] : 0;
        __syncthreads();
        sc[t] += u;
        __syncthreads();
    }
    int excl = sc[t] - h;
    int node = b * 512 + t;
    if (node < N) row_off[node] = ebase + excl;
    hist[t] = ebase + excl;  // reuse as scatter counters
    __syncthreads();
    for (int i = t; i < ne; i += 512) {
        int v = parr[ebase + i];
        int slot = atomicAdd(&hist[(v >> 17) & 511], 1);
        col[slot] = v & 0x1FFFF;
    }
}

// Per src-bucket: LDS hist of out-degrees -> norm = 1/max(deg,1).
__global__ __launch_bounds__(512)
void k3_src(const unsigned short* __restrict__ sarr, const int* __restrict__ totals_s,
            const int* __restrict__ bbase_s, float* __restrict__ norm, int N) {
    __shared__ int hist[512];
    int b = blockIdx.x, t = threadIdx.x;
    int ne = totals_s[b];
    int sb = bbase_s[b];
    hist[t] = 0;
    __syncthreads();
    for (int i = t; i < ne; i += 512)
        atomicAdd(&hist[sarr[sb + i]], 1);
    __syncthreads();
    int node = b * 512 + t;
    if (node < N) {
        int d = hist[t];
        norm[node] = 1.0f / (float)(d > 1 ? d : 1);
    }
}

// Pre-transpose + pre-convert weights to bf16, fragment-contiguous.
__global__ __launch_bounds__(256)
void k_wprep(const float* __restrict__ Wsh, const float* __restrict__ Wmu,
             const float* __restrict__ Wls, unsigned short* __restrict__ W1T,
             unsigned short* __restrict__ W2T) {
    int b = blockIdx.x, t = threadIdx.x;
    if (b < 128) {
        W1T[(size_t)b * 256 + t] = f2bf(Wsh[(size_t)t * 128 + b]);
    } else {
        int n = b - 128;
        if (t < 128) {
            float v = (n < 64) ? Wmu[(size_t)t * 64 + n]
                               : Wls[(size_t)t * 64 + (n - 64)];
            W2T[(size_t)n * 128 + t] = f2bf(v);
        }
    }
}

// GEMM1: outb[M,128](bf16) = (feat[M,256] fp32 @ W) * norm
// A-tile (64x256 fp32 = 64KB) staged async via global_load_lds, +16B/row pad.
__global__ __launch_bounds__(256)
void k_gemm1(const float* __restrict__ A, int M,
             const unsigned short* __restrict__ W1T,
             const float* __restrict__ norm, unsigned short* __restrict__ outb) {
    __shared__ char ldsA[64 * 1040];
    const int w = threadIdx.x >> 6;
    const int lane = threadIdx.x & 63;
    const int quad = lane >> 4;
    const int l16 = lane & 15;
    const int cl = w * 16 + l16;
    const int r0 = blockIdx.x * 64;

#pragma unroll
    for (int i = 0; i < 16; ++i) {
        int row = r0 + w * 16 + i;
        if (row >= M) row = M - 1;
        const char* g = (const char*)A + (size_t)row * 1024 + lane * 16;
        char* l = ldsA + (w * 16 + i) * 1040 + lane * 16;
        gl_lds16(g, l);
    }

    short8 bw[2][8];
#pragma unroll
    for (int hf = 0; hf < 2; ++hf) {
        const unsigned short* wp = W1T + (size_t)(hf * 64 + cl) * 256 + quad * 8;
#pragma unroll
        for (int ks = 0; ks < 8; ++ks)
            bw[hf][ks] = *(const short8*)(wp + ks * 32);
    }
    __syncthreads();

    f32x4 acc[4][2];
#pragma unroll
    for (int m = 0; m < 4; ++m) {
        acc[m][0] = (f32x4){0.f, 0.f, 0.f, 0.f};
        acc[m][1] = (f32x4){0.f, 0.f, 0.f, 0.f};
    }
#pragma unroll
    for (int ks = 0; ks < 8; ++ks) {
#pragma unroll
        for (int m = 0; m < 4; ++m) {
            const float* pr = (const float*)(ldsA + (m * 16 + l16) * 1040 +
                                             (ks * 32 + quad * 8) * 4);
            float4 x = *(const float4*)pr;
            float4 y = *(const float4*)(pr + 4);
            union { short8 v; unsigned int u[4]; } c;
            c.u[0] = f2bf2(x.x, x.y);
            c.u[1] = f2bf2(x.z, x.w);
            c.u[2] = f2bf2(y.x, y.y);
            c.u[3] = f2bf2(y.z, y.w);
            acc[m][0] = __builtin_amdgcn_mfma_f32_16x16x32_bf16(bw[0][ks], c.v, acc[m][0], 0, 0, 0);
            acc[m][1] = __builtin_amdgcn_mfma_f32_16x16x32_bf16(bw[1][ks], c.v, acc[m][1], 0, 0, 0);
        }
    }
    const int colbase = w * 16 + quad * 4;
#pragma unroll
    for (int m = 0; m < 4; ++m) {
        int row = r0 + m * 16 + l16;
        if (row < M) {
            float nm = norm[row];
            ushort4 o0, o1;
            o0.x = f2bf(acc[m][0][0] * nm); o0.y = f2bf(acc[m][0][1] * nm);
            o0.z = f2bf(acc[m][0][2] * nm); o0.w = f2bf(acc[m][0][3] * nm);
            o1.x = f2bf(acc[m][1][0] * nm); o1.y = f2bf(acc[m][1][1] * nm);
            o1.z = f2bf(acc[m][1][2] * nm); o1.w = f2bf(acc[m][1][3] * nm);
            *(ushort4*)&outb[(size_t)row * 128 + colbase] = o0;
            *(ushort4*)&outb[(size_t)row * 128 + 64 + colbase] = o1;
        }
    }
}

// GEMM2: outb[M,128](bf16) = (h[M,128](bf16) @ [Wmu|Wls]) * norm.
__global__ __launch_bounds__(256)
void k_gemm2(const unsigned short* __restrict__ A, int M,
             const unsigned short* __restrict__ W2T,
             const float* __restrict__ norm, unsigned short* __restrict__ outb) {
    __shared__ char ldsB[16 * 1040];
    const int w = threadIdx.x >> 6;
    const int lane = threadIdx.x & 63;
    const int quad = lane >> 4;
    const int l16 = lane & 15;
    const int cl = w * 16 + l16;
    const int r0 = blockIdx.x * 64;

#pragma unroll
    for (int i = 0; i < 4; ++i) {
        int c = w * 4 + i;
        int crow = r0 + c * 4;
        if (crow + 4 > M) crow = M - 4;
        const char* g = (const char*)A + (size_t)crow * 256 + lane * 16;
        char* l = ldsB + c * 1040 + lane * 16;
        gl_lds16(g, l);
    }

    short8 bw[2][4];
#pragma unroll
    for (int hf = 0; hf < 2; ++hf) {
        const unsigned short* wp = W2T + (size_t)(hf * 64 + cl) * 128 + quad * 8;
#pragma unroll
        for (int ks = 0; ks < 4; ++ks)
            bw[hf][ks] = *(const short8*)(wp + ks * 32);
    }
    __syncthreads();

    f32x4 acc[4][2];
#pragma unroll
    for (int m = 0; m < 4; ++m) {
        acc[m][0] = (f32x4){0.f, 0.f, 0.f, 0.f};
        acc[m][1] = (f32x4){0.f, 0.f, 0.f, 0.f};
    }
#pragma unroll
    for (int ks = 0; ks < 4; ++ks) {
#pragma unroll
        for (int m = 0; m < 4; ++m) {
            int row = m * 16 + l16;
            short8 af = *(const short8*)(ldsB + (row >> 2) * 1040 + (row & 3) * 256 +
                                         (ks * 32 + quad * 8) * 2);
            acc[m][0] = __builtin_amdgcn_mfma_f32_16x16x32_bf16(bw[0][ks], af, acc[m][0], 0, 0, 0);
            acc[m][1] = __builtin_amdgcn_mfma_f32_16x16x32_bf16(bw[1][ks], af, acc[m][1], 0, 0, 0);
        }
    }
    const int colbase = w * 16 + quad * 4;
#pragma unroll
    for (int m = 0; m < 4; ++m) {
        int row = r0 + m * 16 + l16;
        if (row < M) {
            float nm = norm[row];
            ushort4 o0, o1;
            o0.x = f2bf(acc[m][0][0] * nm); o0.y = f2bf(acc[m][0][1] * nm);
            o0.z = f2bf(acc[m][0][2] * nm); o0.w = f2bf(acc[m][0][3] * nm);
            o1.x = f2bf(acc[m][1][0] * nm); o1.y = f2bf(acc[m][1][1] * nm);
            o1.z = f2bf(acc[m][1][2] * nm); o1.w = f2bf(acc[m][1][3] * nm);
            *(ushort4*)&outb[(size_t)row * 128 + colbase] = o0;
            *(ushort4*)&outb[(size_t)row * 128 + 64 + colbase] = o1;
        }
    }
}

// SpMM stage 1: half-wave (32 lanes x ushort4 = 256B bf16 row) per node.
__global__ __launch_bounds__(256)
void k_spmm_relu(const int* __restrict__ row_off, const int* __restrict__ col,
                 const unsigned short* __restrict__ hxb, const float* __restrict__ bias,
                 unsigned short* __restrict__ hb, int N) {
    int g = (blockIdx.x * blockDim.x + threadIdx.x) >> 5;
    int l = threadIdx.x & 31;
    if (g >= N) return;
    int e0 = row_off[g], e1 = row_off[g + 1];
    const ushort4* base = (const ushort4*)hxb;
    float4 acc = make_float4(0.f, 0.f, 0.f, 0.f);
    int e = e0;
    for (; e + 7 < e1; e += 8) {
        ushort4 v0 = base[(size_t)col[e] * 32 + l];
        ushort4 v1 = base[(size_t)col[e + 1] * 32 + l];
        ushort4 v2 = base[(size_t)col[e + 2] * 32 + l];
        ushort4 v3 = base[(size_t)col[e + 3] * 32 + l];
        ushort4 v4 = base[(size_t)col[e + 4] * 32 + l];
        ushort4 v5 = base[(size_t)col[e + 5] * 32 + l];
        ushort4 v6 = base[(size_t)col[e + 6] * 32 + l];
        ushort4 v7 = base[(size_t)col[e + 7] * 32 + l];
        acc.x += ((b2f(v0.x) + b2f(v1.x)) + (b2f(v2.x) + b2f(v3.x))) +
                 ((b2f(v4.x) + b2f(v5.x)) + (b2f(v6.x) + b2f(v7.x)));
        acc.y += ((b2f(v0.y) + b2f(v1.y)) + (b2f(v2.y) + b2f(v3.y))) +
                 ((b2f(v4.y) + b2f(v5.y)) + (b2f(v6.y) + b2f(v7.y)));
        acc.z += ((b2f(v0.z) + b2f(v1.z)) + (b2f(v2.z) + b2f(v3.z))) +
                 ((b2f(v4.z) + b2f(v5.z)) + (b2f(v6.z) + b2f(v7.z)));
        acc.w += ((b2f(v0.w) + b2f(v1.w)) + (b2f(v2.w) + b2f(v3.w))) +
                 ((b2f(v4.w) + b2f(v5.w)) + (b2f(v6.w) + b2f(v7.w)));
    }
    for (; e + 1 < e1; e += 2) {
        ushort4 a = base[(size_t)col[e] * 32 + l];
        ushort4 b = base[(size_t)col[e + 1] * 32 + l];
        acc.x += b2f(a.x) + b2f(b.x);
        acc.y += b2f(a.y) + b2f(b.y);
        acc.z += b2f(a.z) + b2f(b.z);
        acc.w += b2f(a.w) + b2f(b.w);
    }
    if (e < e1) {
        ushort4 a = base[(size_t)col[e] * 32 + l];
        acc.x += b2f(a.x); acc.y += b2f(a.y); acc.z += b2f(a.z); acc.w += b2f(a.w);
    }
    float4 bi = ((const float4*)bias)[l];
    ushort4 r;
    r.x = f2bf(fmaxf(acc.x + bi.x, 0.f));
    r.y = f2bf(fmaxf(acc.y + bi.y, 0.f));
    r.z = f2bf(fmaxf(acc.z + bi.z, 0.f));
    r.w = f2bf(fmaxf(acc.w + bi.w, 0.f));
    ((ushort4*)hb)[(size_t)g * 32 + l] = r;
}

// SpMM stage 2 + reparameterization. Lane l<16: mu cols 4l..4l+3; lane l+16: ls.
__global__ __launch_bounds__(256)
void k_spmm_out(const int* __restrict__ row_off, const int* __restrict__ col,
                const unsigned short* __restrict__ hcb, const float* __restrict__ bmu,
                const float* __restrict__ bls, const float* __restrict__ noise,
                float* __restrict__ out, int N) {
    int g = (blockIdx.x * blockDim.x + threadIdx.x) >> 5;
    int l = threadIdx.x & 31;
    if (g >= N) return;
    int e0 = row_off[g], e1 = row_off[g + 1];
    const ushort4* base = (const ushort4*)hcb;
    float4 acc = make_float4(0.f, 0.f, 0.f, 0.f);
    int e = e0;
    for (; e + 7 < e1; e += 8) {
        ushort4 v0 = base[(size_t)col[e] * 32 + l];
        ushort4 v1 = base[(size_t)col[e + 1] * 32 + l];
        ushort4 v2 = base[(size_t)col[e + 2] * 32 + l];
        ushort4 v3 = base[(size_t)col[e + 3] * 32 + l];
        ushort4 v4 = base[(size_t)col[e + 4] * 32 + l];
        ushort4 v5 = base[(size_t)col[e + 5] * 32 + l];
        ushort4 v6 = base[(size_t)col[e + 6] * 32 + l];
        ushort4 v7 = base[(size_t)col[e + 7] * 32 + l];
        acc.x += ((b2f(v0.x) + b2f(v1.x)) + (b2f(v2.x) + b2f(v3.x))) +
                 ((b2f(v4.x) + b2f(v5.x)) + (b2f(v6.x) + b2f(v7.x)));
        acc.y += ((b2f(v0.y) + b2f(v1.y)) + (b2f(v2.y) + b2f(v3.y))) +
                 ((b2f(v4.y) + b2f(v5.y)) + (b2f(v6.y) + b2f(v7.y)));
        acc.z += ((b2f(v0.z) + b2f(v1.z)) + (b2f(v2.z) + b2f(v3.z))) +
                 ((b2f(v4.z) + b2f(v5.z)) + (b2f(v6.z) + b2f(v7.z)));
        acc.w += ((b2f(v0.w) + b2f(v1.w)) + (b2f(v2.w) + b2f(v3.w))) +
                 ((b2f(v4.w) + b2f(v5.w)) + (b2f(v6.w) + b2f(v7.w)));
    }
    for (; e + 1 < e1; e += 2) {
        ushort4 a = base[(size_t)col[e] * 32 + l];
        ushort4 b = base[(size_t)col[e + 1] * 32 + l];
        acc.x += b2f(a.x) + b2f(b.x);
        acc.y += b2f(a.y) + b2f(b.y);
        acc.z += b2f(a.z) + b2f(b.z);
        acc.w += b2f(a.w) + b2f(b.w);
    }
    if (e < e1) {
        ushort4 a = base[(size_t)col[e] * 32 + l];
        acc.x += b2f(a.x); acc.y += b2f(a.y); acc.z += b2f(a.z); acc.w += b2f(a.w);
    }
    int lane64 = threadIdx.x & 63;
    int p = (lane64 + 16) & 63;
    float lx = __shfl(acc.x, p, 64);
    float ly = __shfl(acc.y, p, 64);
    float lz = __shfl(acc.z, p, 64);
    float lw = __shfl(acc.w, p, 64);
    if (l < 16) {
        float4 bm = ((const float4*)bmu)[l];
        float4 bl = ((const float4*)bls)[l];
        float4 nz = ((const float4*)noise)[(size_t)g * 16 + l];
        float4 o;
        o.x = (acc.x + bm.x) + nz.x * expf(lx + bl.x);
        o.y = (acc.y + bm.y) + nz.y * expf(ly + bl.y);
        o.z = (acc.z + bm.z) + nz.z * expf(lz + bl.z);
        o.w = (acc.w + bm.w) + nz.w * expf(lw + bl.w);
        ((float4*)out)[(size_t)g * 16 + l] = o;
    }
}

static inline char* align64(char* p) {
    return (char*)(((uintptr_t)p + 63) & ~(uintptr_t)63);
}

extern "C" void kernel_launch(void* const* d_in, const int* in_sizes, int n_in,
                              void* d_out, int out_size, void* d_ws, size_t ws_size,
                              hipStream_t stream) {
    const float* feat  = (const float*)d_in[0];
    const float* Wsh   = (const float*)d_in[1];
    const float* bsh   = (const float*)d_in[2];
    const float* Wmu   = (const float*)d_in[3];
    const float* bmu   = (const float*)d_in[4];
    const float* Wls   = (const float*)d_in[5];
    const float* bls   = (const float*)d_in[6];
    const float* noise = (const float*)d_in[7];
    const int*   src   = (const int*)d_in[8];
    const int*   dst   = (const int*)d_in[9];
    float* out = (float*)d_out;

    const int N = in_sizes[0] / 256;   // 100000 (<=131072 for 256 buckets of 512)
    const int E = in_sizes[8];         // 1600000
    const int PB = (E + EB - 1) / EB;  // 196

    char* p = (char*)d_ws;
    float* norm   = (float*)p;                  p += (size_t)N * 4;         p = align64(p);
    int* row_off  = (int*)p;                    p += (size_t)(N + 4) * 4;   p = align64(p);
    int* totals   = (int*)p;                    p += 512 * 4;
    int* bbase_d  = (int*)p;                    p += 256 * 4;
    int* bbase_s  = (int*)p;                    p += 256 * 4;               p = align64(p);
    unsigned short* W1T = (unsigned short*)p;   p += (size_t)128 * 256 * 2; // 64 KB
    unsigned short* W2T = (unsigned short*)p;   p += (size_t)128 * 128 * 2; // 32 KB
    p = align64(p);
    int* bhist    = (int*)p;                    p += (size_t)PB * 512 * 4;  p = align64(p);
    int* boffT    = (int*)p;                    p += (size_t)512 * PB * 4;  p = align64(p);
    int* parr     = (int*)p;                    p += (size_t)E * 4;
    unsigned short* sarr = (unsigned short*)p;  p += (size_t)E * 2;         p = align64(p);
    int* col      = (int*)p;                    p += (size_t)E * 4;         p = align64(p);
    unsigned short* hxb = (unsigned short*)p;                  // N*128 bf16 (hx, then hc)
    unsigned short* hb  = (unsigned short*)d_out;              // N*128 bf16 scratch

    // ---- CSR build (no global atomics) ----
    k_wprep<<<256, 256, 0, stream>>>(Wsh, Wmu, Wls, W1T, W2T);
    k1_hist<<<PB, 256, 0, stream>>>(src, dst, bhist, E);
    kc12<<<1, 1024, 0, stream>>>(bhist, totals, bbase_d, bbase_s, PB);
    kc3_boff<<<512, 256, 0, stream>>>(bhist, bbase_d, bbase_s, boffT, PB);
    k2_scatter<<<PB, 256, 0, stream>>>(src, dst, boffT, parr, sarr, E, PB);
    k3_dst<<<NBKT, 512, 0, stream>>>(parr, totals, bbase_d, row_off, col, N, E);
    k3_src<<<NBKT, 512, 0, stream>>>(sarr, totals + 256, bbase_s, norm, N);

    // ---- dense pipeline ----
    int gtiles = (N + 63) / 64;  // 1563
    k_gemm1<<<gtiles, 256, 0, stream>>>(feat, N, W1T, norm, hxb);
    k_spmm_relu<<<(N * 32 + 255) / 256, 256, 0, stream>>>(row_off, col, hxb, bsh, hb, N);
    k_gemm2<<<gtiles, 256, 0, stream>>>(hb, N, W2T, norm, hxb);
    k_spmm_out<<<(N * 32 + 255) / 256, 256, 0, stream>>>(row_off, col, hxb, bmu, bls, noise, out, N);
}

// Round 10
// 450.154 us; speedup vs baseline: 1.0015x; 1.0015x over previous
//
#include <hip/hip_runtime.h>
#include <hip/hip_bf16.h>
#include <math.h>

typedef __attribute__((ext_vector_type(8))) short short8;
typedef __attribute__((ext_vector_type(4))) float f32x4;

// fp32 -> bf16 round-to-nearest-even (scalar)
__device__ __forceinline__ unsigned short f2bf(float f) {
    unsigned int u = __float_as_uint(f);
    u += 0x7FFF + ((u >> 16) & 1);
    return (unsigned short)(u >> 16);
}
__device__ __forceinline__ float b2f(unsigned short s) {
    return __uint_as_float(((unsigned int)s) << 16);
}
// packed fp32x2 -> bf16x2 RNE (v_cvt_pk_bf16_f32 on gfx950)
__device__ __forceinline__ unsigned int f2bf2(float a, float b) {
    __hip_bfloat162 h = __float22bfloat162_rn(make_float2(a, b));
    return *(unsigned int*)&h;
}
// async global->LDS, 16B per lane (global_load_lds_dwordx4)
__device__ __forceinline__ void gl_lds16(const void* g, void* l) {
    __builtin_amdgcn_global_load_lds(
        (const __attribute__((address_space(1))) void*)g,
        (__attribute__((address_space(3))) void*)l, 16, 0, 0);
}

// CSR build via LDS two-level bucket sort, ZERO global atomics.
// 256 buckets x 512 nodes (covers N<=131072). bins 0..255 = dst, 256..511 = src.
// parr packed: src | (dst&511)<<17  (src < 2^17). sarr: ushort (src&511).
#define EB 8192        // edges per partition block
#define BSH 9          // node >> 9 = bucket
#define NBKT 256

__global__ __launch_bounds__(256)
void k1_hist(const int* __restrict__ src, const int* __restrict__ dst,
             int* __restrict__ bhist, int E) {
    __shared__ int hist[512];
    int t = threadIdx.x;
    hist[t] = 0; hist[t + 256] = 0;
    __syncthreads();
    int base = blockIdx.x * EB;
    int end = min(base + EB, E);
    for (int e = base + 4 * t; e < end; e += 1024) {
        if (e + 3 < end) {
            int4 d4 = *(const int4*)&dst[e];
            int4 s4 = *(const int4*)&src[e];
            atomicAdd(&hist[d4.x >> BSH], 1);
            atomicAdd(&hist[d4.y >> BSH], 1);
            atomicAdd(&hist[d4.z >> BSH], 1);
            atomicAdd(&hist[d4.w >> BSH], 1);
            atomicAdd(&hist[256 + (s4.x >> BSH)], 1);
            atomicAdd(&hist[256 + (s4.y >> BSH)], 1);
            atomicAdd(&hist[256 + (s4.z >> BSH)], 1);
            atomicAdd(&hist[256 + (s4.w >> BSH)], 1);
        } else {
            for (int q = e; q < end; ++q) {
                atomicAdd(&hist[dst[q] >> BSH], 1);
                atomicAdd(&hist[256 + (src[q] >> BSH)], 1);
            }
        }
    }
    __syncthreads();
    int* o = bhist + (size_t)blockIdx.x * 512;
    o[t] = hist[t];
    o[t + 256] = hist[t + 256];
}

// Fused: column totals over PB blocks + segmented exclusive scan (dst|src).
__global__ __launch_bounds__(1024)
void kc12(const int* __restrict__ bhist, int* __restrict__ totals,
          int* __restrict__ bbase_d, int* __restrict__ bbase_s, int PB) {
    __shared__ int part[1024];
    __shared__ int s[512];
    int t = threadIdx.x;
    int bin = t & 511, half = t >> 9;
    int sum = 0;
    for (int blk = half; blk < PB; blk += 2)
        sum += bhist[(size_t)blk * 512 + bin];
    part[t] = sum;
    __syncthreads();
    int v = 0;
    if (t < 512) {
        v = part[t] + part[t + 512];
        totals[t] = v;
        s[t] = v;
    }
    __syncthreads();
    for (int off = 1; off < 256; off <<= 1) {
        int u = 0;
        if (t < 512 && (t & 255) >= off) u = s[t - off];
        __syncthreads();
        if (t < 512) s[t] += u;
        __syncthreads();
    }
    if (t < 512) {
        int excl = s[t] - v;
        if (t < 256) bbase_d[t] = excl;
        else bbase_s[t - 256] = excl;
    }
}

// Per-bin scan over partition blocks -> boffT[bin][PB]; blocks >=512 do the
// weight transpose/convert (merged k_wprep: saves a launch+drain).
__global__ __launch_bounds__(256)
void kc3_boff(const int* __restrict__ bhist, const int* __restrict__ bbase_d,
              const int* __restrict__ bbase_s, int* __restrict__ boffT, int PB,
              const float* __restrict__ Wsh, const float* __restrict__ Wmu,
              const float* __restrict__ Wls, unsigned short* __restrict__ W1T,
              unsigned short* __restrict__ W2T) {
    int b = blockIdx.x;
    int t = threadIdx.x;
    if (b >= 512) {
        int wb = b - 512;
        if (wb < 128) {
            W1T[(size_t)wb * 256 + t] = f2bf(Wsh[(size_t)t * 128 + wb]);
        } else {
            int n = wb - 128;
            if (t < 128) {
                float v = (n < 64) ? Wmu[(size_t)t * 64 + n]
                                   : Wls[(size_t)t * 64 + (n - 64)];
                W2T[(size_t)n * 128 + t] = f2bf(v);
            }
        }
        return;
    }
    __shared__ int sums[256];
    int v = (t < PB) ? bhist[(size_t)t * 512 + b] : 0;
    sums[t] = v;
    __syncthreads();
    for (int off = 1; off < 256; off <<= 1) {
        int u = (t >= off) ? sums[t - off] : 0;
        __syncthreads();
        sums[t] += u;
        __syncthreads();
    }
    int base = (b < 256) ? bbase_d[b] : bbase_s[b - 256];
    if (t < PB) boffT[(size_t)b * PB + t] = base + sums[t] - v;
}

__global__ __launch_bounds__(256)
void k2_scatter(const int* __restrict__ src, const int* __restrict__ dst,
                const int* __restrict__ boffT, int* __restrict__ parr,
                unsigned short* __restrict__ sarr, int E, int PB) {
    __shared__ int cnt[512];
    int t = threadIdx.x;
    int blk = blockIdx.x;
    cnt[t] = boffT[(size_t)t * PB + blk];
    cnt[t + 256] = boffT[(size_t)(t + 256) * PB + blk];
    __syncthreads();
    int base = blk * EB;
    int end = min(base + EB, E);
    for (int e = base + 4 * t; e < end; e += 1024) {
        if (e + 3 < end) {
            int4 s4 = *(const int4*)&src[e];
            int4 d4 = *(const int4*)&dst[e];
            int p0 = atomicAdd(&cnt[d4.x >> BSH], 1); parr[p0] = s4.x | ((d4.x & 511) << 17);
            int p1 = atomicAdd(&cnt[d4.y >> BSH], 1); parr[p1] = s4.y | ((d4.y & 511) << 17);
            int p2 = atomicAdd(&cnt[d4.z >> BSH], 1); parr[p2] = s4.z | ((d4.z & 511) << 17);
            int p3 = atomicAdd(&cnt[d4.w >> BSH], 1); parr[p3] = s4.w | ((d4.w & 511) << 17);
            int q0 = atomicAdd(&cnt[256 + (s4.x >> BSH)], 1); sarr[q0] = (unsigned short)(s4.x & 511);
            int q1 = atomicAdd(&cnt[256 + (s4.y >> BSH)], 1); sarr[q1] = (unsigned short)(s4.y & 511);
            int q2 = atomicAdd(&cnt[256 + (s4.z >> BSH)], 1); sarr[q2] = (unsigned short)(s4.z & 511);
            int q3 = atomicAdd(&cnt[256 + (s4.w >> BSH)], 1); sarr[q3] = (unsigned short)(s4.w & 511);
        } else {
            for (int q = e; q < end; ++q) {
                int sv = src[q], dv = dst[q];
                int pd = atomicAdd(&cnt[dv >> BSH], 1);
                parr[pd] = sv | ((dv & 511) << 17);
                int ps = atomicAdd(&cnt[256 + (sv >> BSH)], 1);
                sarr[ps] = (unsigned short)(sv & 511);
            }
        }
    }
}

// Per dst-bucket (512 nodes): LDS 512-bin hist + scan -> row_off, col.
__global__ __launch_bounds__(512)
void k3_dst(const int* __restrict__ parr, const int* __restrict__ totals,
            const int* __restrict__ bbase_d, int* __restrict__ row_off,
            int* __restrict__ col, int N, int E) {
    __shared__ int hist[512], sc[512];
    int b = blockIdx.x, t = threadIdx.x;
    if (b == 0 && t == 0) row_off[N] = E;
    int ne = totals[b];
    int ebase = bbase_d[b];
    hist[t] = 0;
    __syncthreads();
    for (int i = t; i < ne; i += 512)
        atomicAdd(&hist[(parr[ebase + i] >> 17) & 511], 1);
    __syncthreads();
    int h = hist[t];
    sc[t] = h;
    __syncthreads();
    for (int off = 1; off < 512; off <<= 1) {
        int u = (t >= off) ? sc[t - off] : 0;
        __syncthreads();
        sc[t] += u;
        __syncthreads();
    }
    int excl = sc[t] - h;
    int node = b * 512 + t;
    if (node < N) row_off[node] = ebase + excl;
    hist[t] = ebase + excl;  // reuse as scatter counters
    __syncthreads();
    for (int i = t; i < ne; i += 512) {
        int v = parr[ebase + i];
        int slot = atomicAdd(&hist[(v >> 17) & 511], 1);
        col[slot] = v & 0x1FFFF;
    }
}

// Per src-bucket: LDS hist of out-degrees -> norm = 1/max(deg,1).
__global__ __launch_bounds__(512)
void k3_src(const unsigned short* __restrict__ sarr, const int* __restrict__ totals_s,
            const int* __restrict__ bbase_s, float* __restrict__ norm, int N) {
    __shared__ int hist[512];
    int b = blockIdx.x, t = threadIdx.x;
    int ne = totals_s[b];
    int sb = bbase_s[b];
    hist[t] = 0;
    __syncthreads();
    for (int i = t; i < ne; i += 512)
        atomicAdd(&hist[sarr[sb + i]], 1);
    __syncthreads();
    int node = b * 512 + t;
    if (node < N) {
        int d = hist[t];
        norm[node] = 1.0f / (float)(d > 1 ? d : 1);
    }
}

// GEMM1: outb[M,128](bf16) = (feat[M,256] fp32 @ W) * norm
// 32-row tile, 33KB LDS -> 4 blocks/CU (R8's 64-row/65KB tile capped at
// 2 blocks/CU; both phase-locked at the staging vmcnt(0) barrier and the CU
// idled for full HBM latency each tile). Wave w stages rows w*8..w*8+7 and
// computes col group w*16 over both 16-row m-tiles.
__global__ __launch_bounds__(256, 4)
void k_gemm1(const float* __restrict__ A, int M,
             const unsigned short* __restrict__ W1T,
             const float* __restrict__ norm, unsigned short* __restrict__ outb) {
    __shared__ char ldsA[32 * 1040];
    const int w = threadIdx.x >> 6;
    const int lane = threadIdx.x & 63;
    const int quad = lane >> 4;
    const int l16 = lane & 15;
    const int cl = w * 16 + l16;
    const int r0 = blockIdx.x * 32;

#pragma unroll
    for (int i = 0; i < 8; ++i) {
        int row = r0 + w * 8 + i;
        if (row >= M) row = M - 1;
        const char* g = (const char*)A + (size_t)row * 1024 + lane * 16;
        char* l = ldsA + (w * 8 + i) * 1040 + lane * 16;
        gl_lds16(g, l);
    }

    short8 bw[2][8];
#pragma unroll
    for (int hf = 0; hf < 2; ++hf) {
        const unsigned short* wp = W1T + (size_t)(hf * 64 + cl) * 256 + quad * 8;
#pragma unroll
        for (int ks = 0; ks < 8; ++ks)
            bw[hf][ks] = *(const short8*)(wp + ks * 32);
    }
    __syncthreads();

    f32x4 acc[2][2];
#pragma unroll
    for (int m = 0; m < 2; ++m) {
        acc[m][0] = (f32x4){0.f, 0.f, 0.f, 0.f};
        acc[m][1] = (f32x4){0.f, 0.f, 0.f, 0.f};
    }
#pragma unroll
    for (int ks = 0; ks < 8; ++ks) {
#pragma unroll
        for (int m = 0; m < 2; ++m) {
            const float* pr = (const float*)(ldsA + (m * 16 + l16) * 1040 +
                                             (ks * 32 + quad * 8) * 4);
            float4 x = *(const float4*)pr;
            float4 y = *(const float4*)(pr + 4);
            union { short8 v; unsigned int u[4]; } c;
            c.u[0] = f2bf2(x.x, x.y);
            c.u[1] = f2bf2(x.z, x.w);
            c.u[2] = f2bf2(y.x, y.y);
            c.u[3] = f2bf2(y.z, y.w);
            acc[m][0] = __builtin_amdgcn_mfma_f32_16x16x32_bf16(bw[0][ks], c.v, acc[m][0], 0, 0, 0);
            acc[m][1] = __builtin_amdgcn_mfma_f32_16x16x32_bf16(bw[1][ks], c.v, acc[m][1], 0, 0, 0);
        }
    }
    const int colbase = w * 16 + quad * 4;
#pragma unroll
    for (int m = 0; m < 2; ++m) {
        int row = r0 + m * 16 + l16;
        if (row < M) {
            float nm = norm[row];
            ushort4 o0, o1;
            o0.x = f2bf(acc[m][0][0] * nm); o0.y = f2bf(acc[m][0][1] * nm);
            o0.z = f2bf(acc[m][0][2] * nm); o0.w = f2bf(acc[m][0][3] * nm);
            o1.x = f2bf(acc[m][1][0] * nm); o1.y = f2bf(acc[m][1][1] * nm);
            o1.z = f2bf(acc[m][1][2] * nm); o1.w = f2bf(acc[m][1][3] * nm);
            *(ushort4*)&outb[(size_t)row * 128 + colbase] = o0;
            *(ushort4*)&outb[(size_t)row * 128 + 64 + colbase] = o1;
        }
    }
}

// GEMM2: outb[M,128](bf16) = (h[M,128](bf16) @ [Wmu|Wls]) * norm. 17KB LDS.
__global__ __launch_bounds__(256)
void k_gemm2(const unsigned short* __restrict__ A, int M,
             const unsigned short* __restrict__ W2T,
             const float* __restrict__ norm, unsigned short* __restrict__ outb) {
    __shared__ char ldsB[16 * 1040];
    const int w = threadIdx.x >> 6;
    const int lane = threadIdx.x & 63;
    const int quad = lane >> 4;
    const int l16 = lane & 15;
    const int cl = w * 16 + l16;
    const int r0 = blockIdx.x * 64;

#pragma unroll
    for (int i = 0; i < 4; ++i) {
        int c = w * 4 + i;
        int crow = r0 + c * 4;
        if (crow + 4 > M) crow = M - 4;
        const char* g = (const char*)A + (size_t)crow * 256 + lane * 16;
        char* l = ldsB + c * 1040 + lane * 16;
        gl_lds16(g, l);
    }

    short8 bw[2][4];
#pragma unroll
    for (int hf = 0; hf < 2; ++hf) {
        const unsigned short* wp = W2T + (size_t)(hf * 64 + cl) * 128 + quad * 8;
#pragma unroll
        for (int ks = 0; ks < 4; ++ks)
            bw[hf][ks] = *(const short8*)(wp + ks * 32);
    }
    __syncthreads();

    f32x4 acc[4][2];
#pragma unroll
    for (int m = 0; m < 4; ++m) {
        acc[m][0] = (f32x4){0.f, 0.f, 0.f, 0.f};
        acc[m][1] = (f32x4){0.f, 0.f, 0.f, 0.f};
    }
#pragma unroll
    for (int ks = 0; ks < 4; ++ks) {
#pragma unroll
        for (int m = 0; m < 4; ++m) {
            int row = m * 16 + l16;
            short8 af = *(const short8*)(ldsB + (row >> 2) * 1040 + (row & 3) * 256 +
                                         (ks * 32 + quad * 8) * 2);
            acc[m][0] = __builtin_amdgcn_mfma_f32_16x16x32_bf16(bw[0][ks], af, acc[m][0], 0, 0, 0);
            acc[m][1] = __builtin_amdgcn_mfma_f32_16x16x32_bf16(bw[1][ks], af, acc[m][1], 0, 0, 0);
        }
    }
    const int colbase = w * 16 + quad * 4;
#pragma unroll
    for (int m = 0; m < 4; ++m) {
        int row = r0 + m * 16 + l16;
        if (row < M) {
            float nm = norm[row];
            ushort4 o0, o1;
            o0.x = f2bf(acc[m][0][0] * nm); o0.y = f2bf(acc[m][0][1] * nm);
            o0.z = f2bf(acc[m][0][2] * nm); o0.w = f2bf(acc[m][0][3] * nm);
            o1.x = f2bf(acc[m][1][0] * nm); o1.y = f2bf(acc[m][1][1] * nm);
            o1.z = f2bf(acc[m][1][2] * nm); o1.w = f2bf(acc[m][1][3] * nm);
            *(ushort4*)&outb[(size_t)row * 128 + colbase] = o0;
            *(ushort4*)&outb[(size_t)row * 128 + 64 + colbase] = o1;
        }
    }
}

// SpMM stage 1: half-wave (32 lanes x ushort4 = 256B bf16 row) per node.
__global__ __launch_bounds__(256)
void k_spmm_relu(const int* __restrict__ row_off, const int* __restrict__ col,
                 const unsigned short* __restrict__ hxb, const float* __restrict__ bias,
                 unsigned short* __restrict__ hb, int N) {
    int g = (blockIdx.x * blockDim.x + threadIdx.x) >> 5;
    int l = threadIdx.x & 31;
    if (g >= N) return;
    int e0 = row_off[g], e1 = row_off[g + 1];
    const ushort4* base = (const ushort4*)hxb;
    float4 acc = make_float4(0.f, 0.f, 0.f, 0.f);
    int e = e0;
    for (; e + 7 < e1; e += 8) {
        ushort4 v0 = base[(size_t)col[e] * 32 + l];
        ushort4 v1 = base[(size_t)col[e + 1] * 32 + l];
        ushort4 v2 = base[(size_t)col[e + 2] * 32 + l];
        ushort4 v3 = base[(size_t)col[e + 3] * 32 + l];
        ushort4 v4 = base[(size_t)col[e + 4] * 32 + l];
        ushort4 v5 = base[(size_t)col[e + 5] * 32 + l];
        ushort4 v6 = base[(size_t)col[e + 6] * 32 + l];
        ushort4 v7 = base[(size_t)col[e + 7] * 32 + l];
        acc.x += ((b2f(v0.x) + b2f(v1.x)) + (b2f(v2.x) + b2f(v3.x))) +
                 ((b2f(v4.x) + b2f(v5.x)) + (b2f(v6.x) + b2f(v7.x)));
        acc.y += ((b2f(v0.y) + b2f(v1.y)) + (b2f(v2.y) + b2f(v3.y))) +
                 ((b2f(v4.y) + b2f(v5.y)) + (b2f(v6.y) + b2f(v7.y)));
        acc.z += ((b2f(v0.z) + b2f(v1.z)) + (b2f(v2.z) + b2f(v3.z))) +
                 ((b2f(v4.z) + b2f(v5.z)) + (b2f(v6.z) + b2f(v7.z)));
        acc.w += ((b2f(v0.w) + b2f(v1.w)) + (b2f(v2.w) + b2f(v3.w))) +
                 ((b2f(v4.w) + b2f(v5.w)) + (b2f(v6.w) + b2f(v7.w)));
    }
    for (; e + 1 < e1; e += 2) {
        ushort4 a = base[(size_t)col[e] * 32 + l];
        ushort4 b = base[(size_t)col[e + 1] * 32 + l];
        acc.x += b2f(a.x) + b2f(b.x);
        acc.y += b2f(a.y) + b2f(b.y);
        acc.z += b2f(a.z) + b2f(b.z);
        acc.w += b2f(a.w) + b2f(b.w);
    }
    if (e < e1) {
        ushort4 a = base[(size_t)col[e] * 32 + l];
        acc.x += b2f(a.x); acc.y += b2f(a.y); acc.z += b2f(a.z); acc.w += b2f(a.w);
    }
    float4 bi = ((const float4*)bias)[l];
    ushort4 r;
    r.x = f2bf(fmaxf(acc.x + bi.x, 0.f));
    r.y = f2bf(fmaxf(acc.y + bi.y, 0.f));
    r.z = f2bf(fmaxf(acc.z + bi.z, 0.f));
    r.w = f2bf(fmaxf(acc.w + bi.w, 0.f));
    ((ushort4*)hb)[(size_t)g * 32 + l] = r;
}

// SpMM stage 2 + reparameterization. Lane l<16: mu cols 4l..4l+3; lane l+16: ls.
__global__ __launch_bounds__(256)
void k_spmm_out(const int* __restrict__ row_off, const int* __restrict__ col,
                const unsigned short* __restrict__ hcb, const float* __restrict__ bmu,
                const float* __restrict__ bls, const float* __restrict__ noise,
                float* __restrict__ out, int N) {
    int g = (blockIdx.x * blockDim.x + threadIdx.x) >> 5;
    int l = threadIdx.x & 31;
    if (g >= N) return;
    int e0 = row_off[g], e1 = row_off[g + 1];
    const ushort4* base = (const ushort4*)hcb;
    float4 acc = make_float4(0.f, 0.f, 0.f, 0.f);
    int e = e0;
    for (; e + 7 < e1; e += 8) {
        ushort4 v0 = base[(size_t)col[e] * 32 + l];
        ushort4 v1 = base[(size_t)col[e + 1] * 32 + l];
        ushort4 v2 = base[(size_t)col[e + 2] * 32 + l];
        ushort4 v3 = base[(size_t)col[e + 3] * 32 + l];
        ushort4 v4 = base[(size_t)col[e + 4] * 32 + l];
        ushort4 v5 = base[(size_t)col[e + 5] * 32 + l];
        ushort4 v6 = base[(size_t)col[e + 6] * 32 + l];
        ushort4 v7 = base[(size_t)col[e + 7] * 32 + l];
        acc.x += ((b2f(v0.x) + b2f(v1.x)) + (b2f(v2.x) + b2f(v3.x))) +
                 ((b2f(v4.x) + b2f(v5.x)) + (b2f(v6.x) + b2f(v7.x)));
        acc.y += ((b2f(v0.y) + b2f(v1.y)) + (b2f(v2.y) + b2f(v3.y))) +
                 ((b2f(v4.y) + b2f(v5.y)) + (b2f(v6.y) + b2f(v7.y)));
        acc.z += ((b2f(v0.z) + b2f(v1.z)) + (b2f(v2.z) + b2f(v3.z))) +
                 ((b2f(v4.z) + b2f(v5.z)) + (b2f(v6.z) + b2f(v7.z)));
        acc.w += ((b2f(v0.w) + b2f(v1.w)) + (b2f(v2.w) + b2f(v3.w))) +
                 ((b2f(v4.w) + b2f(v5.w)) + (b2f(v6.w) + b2f(v7.w)));
    }
    for (; e + 1 < e1; e += 2) {
        ushort4 a = base[(size_t)col[e] * 32 + l];
        ushort4 b = base[(size_t)col[e + 1] * 32 + l];
        acc.x += b2f(a.x) + b2f(b.x);
        acc.y += b2f(a.y) + b2f(b.y);
        acc.z += b2f(a.z) + b2f(b.z);
        acc.w += b2f(a.w) + b2f(b.w);
    }
    if (e < e1) {
        ushort4 a = base[(size_t)col[e] * 32 + l];
        acc.x += b2f(a.x); acc.y += b2f(a.y); acc.z += b2f(a.z); acc.w += b2f(a.w);
    }
    int lane64 = threadIdx.x & 63;
    int p = (lane64 + 16) & 63;
    float lx = __shfl(acc.x, p, 64);
    float ly = __shfl(acc.y, p, 64);
    float lz = __shfl(acc.z, p, 64);
    float lw = __shfl(acc.w, p, 64);
    if (l < 16) {
        float4 bm = ((const float4*)bmu)[l];
        float4 bl = ((const float4*)bls)[l];
        float4 nz = ((const float4*)noise)[(size_t)g * 16 + l];
        float4 o;
        o.x = (acc.x + bm.x) + nz.x * expf(lx + bl.x);
        o.y = (acc.y + bm.y) + nz.y * expf(ly + bl.y);
        o.z = (acc.z + bm.z) + nz.z * expf(lz + bl.z);
        o.w = (acc.w + bm.w) + nz.w * expf(lw + bl.w);
        ((float4*)out)[(size_t)g * 16 + l] = o;
    }
}

static inline char* align64(char* p) {
    return (char*)(((uintptr_t)p + 63) & ~(uintptr_t)63);
}

extern "C" void kernel_launch(void* const* d_in, const int* in_sizes, int n_in,
                              void* d_out, int out_size, void* d_ws, size_t ws_size,
                              hipStream_t stream) {
    const float* feat  = (const float*)d_in[0];
    const float* Wsh   = (const float*)d_in[1];
    const float* bsh   = (const float*)d_in[2];
    const float* Wmu   = (const float*)d_in[3];
    const float* bmu   = (const float*)d_in[4];
    const float* Wls   = (const float*)d_in[5];
    const float* bls   = (const float*)d_in[6];
    const float* noise = (const float*)d_in[7];
    const int*   src   = (const int*)d_in[8];
    const int*   dst   = (const int*)d_in[9];
    float* out = (float*)d_out;

    const int N = in_sizes[0] / 256;   // 100000 (<=131072 for 256 buckets of 512)
    const int E = in_sizes[8];         // 1600000
    const int PB = (E + EB - 1) / EB;  // 196

    char* p = (char*)d_ws;
    float* norm   = (float*)p;                  p += (size_t)N * 4;         p = align64(p);
    int* row_off  = (int*)p;                    p += (size_t)(N + 4) * 4;   p = align64(p);
    int* totals   = (int*)p;                    p += 512 * 4;
    int* bbase_d  = (int*)p;                    p += 256 * 4;
    int* bbase_s  = (int*)p;                    p += 256 * 4;               p = align64(p);
    unsigned short* W1T = (unsigned short*)p;   p += (size_t)128 * 256 * 2; // 64 KB
    unsigned short* W2T = (unsigned short*)p;   p += (size_t)128 * 128 * 2; // 32 KB
    p = align64(p);
    int* bhist    = (int*)p;                    p += (size_t)PB * 512 * 4;  p = align64(p);
    int* boffT    = (int*)p;                    p += (size_t)512 * PB * 4;  p = align64(p);
    int* parr     = (int*)p;                    p += (size_t)E * 4;
    unsigned short* sarr = (unsigned short*)p;  p += (size_t)E * 2;         p = align64(p);
    int* col      = (int*)p;                    p += (size_t)E * 4;         p = align64(p);
    unsigned short* hxb = (unsigned short*)p;                  // N*128 bf16 (hx, then hc)
    unsigned short* hb  = (unsigned short*)d_out;              // N*128 bf16 scratch

    // ---- CSR build (no global atomics) ----
    k1_hist<<<PB, 256, 0, stream>>>(src, dst, bhist, E);
    kc12<<<1, 1024, 0, stream>>>(bhist, totals, bbase_d, bbase_s, PB);
    kc3_boff<<<512 + 256, 256, 0, stream>>>(bhist, bbase_d, bbase_s, boffT, PB,
                                            Wsh, Wmu, Wls, W1T, W2T);
    k2_scatter<<<PB, 256, 0, stream>>>(src, dst, boffT, parr, sarr, E, PB);
    k3_dst<<<NBKT, 512, 0, stream>>>(parr, totals, bbase_d, row_off, col, N, E);
    k3_src<<<NBKT, 512, 0, stream>>>(sarr, totals + 256, bbase_s, norm, N);

    // ---- dense pipeline ----
    k_gemm1<<<(N + 31) / 32, 256, 0, stream>>>(feat, N, W1T, norm, hxb);
    k_spmm_relu<<<(N * 32 + 255) / 256, 256, 0, stream>>>(row_off, col, hxb, bsh, hb, N);
    k_gemm2<<<(N + 63) / 64, 256, 0, stream>>>(hb, N, W2T, norm, hxb);
    k_spmm_out<<<(N * 32 + 255) / 256, 256, 0, stream>>>(row_off, col, hxb, bmu, bls, noise, out, N);
}